// Round 5
// baseline (864.675 us; speedup 1.0000x reference)
//
#include <hip/hip_runtime.h>
#include <hip/hip_bf16.h>

// out = (x @ R^T) @ codes^T + bias, codes = codebook[indices]
// Fused single kernel, 2048 blocks x 256 threads, ticket-ordered split-K pipeline:
//   phase A (per block): y_ws += x @ R^T sub-tile (32j x 256k), release flag
//   phase B (per block): out += y @ codes^T sub-tile (64o x 256k), acquire flag
// idx loads (the dominant 128 MB stream) are issued FIRST and stay in flight
// through phase A, overlapping the R stream and the y dependency wait.
// Ticket bands make the spin deadlock-free for any dispatch order with >=128
// co-resident blocks: flag[q] is produced exactly by tickets [128q, 128q+128),
// and ticket t spins on flag[t>>7] (its own band).

#define IN_F 4096
#define OUT_F 8192
#define BATCH 32
#define TS 264   // LDS row stride in bf16 elems: 528 B = 33*16 B

typedef short bf16x8s __attribute__((ext_vector_type(8)));
typedef float f32x4 __attribute__((ext_vector_type(4)));
typedef int   i32x4 __attribute__((ext_vector_type(4)));

__device__ __forceinline__ unsigned short f2bf(float f) {
    union { float f; unsigned int u; } v; v.f = f;
    unsigned int u = v.u;
    return (unsigned short)((u + 0x7fffu + ((u >> 16) & 1u)) >> 16);
}

__global__ void __launch_bounds__(256, 3) fused(const float* __restrict__ x,
                                                const int* __restrict__ idx,
                                                const float* __restrict__ cb,
                                                const float* __restrict__ R,
                                                const float* __restrict__ bias,
                                                float* __restrict__ out,
                                                float* __restrict__ y_ws,
                                                int* __restrict__ flags,   // [16]
                                                int* __restrict__ ticket) {
    __shared__ unsigned short smem[96 * TS];  // A: Rl(32)+Xl(32) | B: Bl(64)+Al(32)
    __shared__ unsigned int cbp[256];
    __shared__ int t_sh;

    const int tid = threadIdx.x;
    if (tid == 0)
        t_sh = __hip_atomic_fetch_add(ticket, 1, __ATOMIC_RELAXED, __HIP_MEMORY_SCOPE_AGENT);
    cbp[tid] = (unsigned int)f2bf(cb[tid & 15]) | ((unsigned int)f2bf(cb[tid >> 4]) << 16);
    __syncthreads();
    const int t = t_sh;

    // role assignment by ticket (NOT blockIdx) — deadlock-free band structure
    const int jt  = t >> 4;            // 0..127  phase-A j-tile (32 wide)
    const int kq1 = t & 15;            //         phase-A k-chunk
    const int ot  = t & 127;           // 0..127  phase-B o-tile (64 wide)
    const int kq2 = t >> 7;            // 0..15   phase-B k-chunk = flag band
    const int j0 = jt * 32, k1_0 = kq1 * 256;
    const int o0 = ot * 64, k2_0 = kq2 * 256;
    const int wave = tid >> 6, lane = tid & 63;
    const int n = lane & 15, quad = lane >> 4;

    // ---- issue idx loads FIRST (stream-once, nontemporal): in flight all of phase A
    i32x4 iv[16];
    #pragma unroll
    for (int jj = 0; jj < 16; ++jj) {
        int f = tid + jj * 256;              // [64 rows][64 int4]
        int row = f >> 6, c4 = f & 63;
        iv[jj] = __builtin_nontemporal_load(
            (const i32x4*)(idx + (size_t)(o0 + row) * IN_F + k2_0 + c4 * 4));
    }

    // ---- phase A staging: R (nontemporal) + x
    f32x4 rv[8], xv[8];
    #pragma unroll
    for (int ii = 0; ii < 8; ++ii) {
        int f = tid + ii * 256;              // [32 rows][64 float4]
        int row = f >> 6, c4 = f & 63;
        rv[ii] = __builtin_nontemporal_load(
            (const f32x4*)(R + (size_t)(j0 + row) * IN_F + k1_0 + c4 * 4));
        xv[ii] = *(const f32x4*)(x + (size_t)row * IN_F + k1_0 + c4 * 4);
    }
    unsigned short* Rl = smem;            // [32][TS]
    unsigned short* Xl = smem + 32 * TS;  // [32][TS]
    #pragma unroll
    for (int ii = 0; ii < 8; ++ii) {
        int f = tid + ii * 256;
        int row = f >> 6, c4 = f & 63;
        ushort4 pr, px;
        pr.x = f2bf(rv[ii].x); pr.y = f2bf(rv[ii].y); pr.z = f2bf(rv[ii].z); pr.w = f2bf(rv[ii].w);
        px.x = f2bf(xv[ii].x); px.y = f2bf(xv[ii].y); px.z = f2bf(xv[ii].z); px.w = f2bf(xv[ii].w);
        *(ushort4*)&Rl[row * TS + c4 * 4] = pr;
        *(ushort4*)&Xl[row * TS + c4 * 4] = px;
    }
    __syncthreads();

    // ---- phase A MFMA: M=32 x N=32, one 16x16 tile per wave, K=256
    {
        const int nh = wave & 1, mh = wave >> 1;
        f32x4 acc = {0.f, 0.f, 0.f, 0.f};
        #pragma unroll
        for (int ks = 0; ks < 8; ++ks) {
            bf16x8s bfr = *(const bf16x8s*)&Rl[(nh * 16 + n) * TS + ks * 32 + quad * 8];
            bf16x8s a   = *(const bf16x8s*)&Xl[(mh * 16 + n) * TS + ks * 32 + quad * 8];
            acc = __builtin_amdgcn_mfma_f32_16x16x32_bf16(a, bfr, acc, 0, 0, 0);
        }
        const int jcol = j0 + nh * 16 + n;
        #pragma unroll
        for (int r = 0; r < 4; ++r)
            atomicAdd(&y_ws[(size_t)(mh * 16 + quad * 4 + r) * IN_F + jcol], acc[r]);
    }
    __threadfence();       // make y atomics visible before the flag release
    __syncthreads();       // all waves' atomics issued; LDS reads done
    if (tid == 0)
        __hip_atomic_fetch_add(&flags[jt >> 3], 1, __ATOMIC_RELEASE, __HIP_MEMORY_SCOPE_AGENT);

    // ---- phase B staging: codes tile from iv (independent of y -> before spin)
    unsigned short* Bl = smem;            // [64][TS]
    unsigned short* Al = smem + 64 * TS;  // [32][TS]
    #pragma unroll
    for (int jj = 0; jj < 16; ++jj) {
        int f = tid + jj * 256;
        int row = f >> 6, c4 = f & 63;
        unsigned int key0 = (unsigned int)iv[jj].x | ((unsigned int)iv[jj].y << 4);
        unsigned int key1 = (unsigned int)iv[jj].z | ((unsigned int)iv[jj].w << 4);
        uint2 pv;
        pv.x = cbp[key0];
        pv.y = cbp[key1];
        *(uint2*)&Bl[row * TS + c4 * 4] = pv;
    }

    // ---- wait for y[:, k2_0..k2_0+255] complete (own ticket band: deadlock-free)
    if (tid == 0) {
        while (__hip_atomic_load(&flags[kq2], __ATOMIC_RELAXED, __HIP_MEMORY_SCOPE_AGENT) < 128)
            __builtin_amdgcn_s_sleep(2);
    }
    __syncthreads();
    __threadfence();       // acquire: invalidate stale cached y lines

    // ---- y load + convert
    #pragma unroll
    for (int ii = 0; ii < 8; ++ii) {
        int f = tid + ii * 256;
        int row = f >> 6, c4 = f & 63;
        const f32x4 v = *(const f32x4*)(y_ws + (size_t)row * IN_F + k2_0 + c4 * 4);
        ushort4 pv;
        pv.x = f2bf(v.x); pv.y = f2bf(v.y); pv.z = f2bf(v.z); pv.w = f2bf(v.w);
        *(ushort4*)&Al[row * TS + c4 * 4] = pv;
    }
    __syncthreads();

    // ---- phase B MFMA: M=32 x N=64, wave n-range wave*16, K=256
    f32x4 c0 = {0.f, 0.f, 0.f, 0.f};
    f32x4 c1 = {0.f, 0.f, 0.f, 0.f};
    #pragma unroll
    for (int ks = 0; ks < 8; ++ks) {
        bf16x8s bfr = *(const bf16x8s*)&Bl[(wave * 16 + n) * TS + ks * 32 + quad * 8];
        bf16x8s a0  = *(const bf16x8s*)&Al[n * TS + ks * 32 + quad * 8];
        bf16x8s a1  = *(const bf16x8s*)&Al[(16 + n) * TS + ks * 32 + quad * 8];
        c0 = __builtin_amdgcn_mfma_f32_16x16x32_bf16(a0, bfr, c0, 0, 0, 0);
        c1 = __builtin_amdgcn_mfma_f32_16x16x32_bf16(a1, bfr, c1, 0, 0, 0);
    }
    const int ocol = o0 + wave * 16 + n;
    const float bv = (kq2 == 0) ? bias[ocol] : 0.f;   // bias added exactly once per out elem
    #pragma unroll
    for (int r = 0; r < 4; ++r) {
        int br = quad * 4 + r;
        atomicAdd(&out[(size_t)br * OUT_F + ocol], c0[r] + bv);
        atomicAdd(&out[(size_t)(br + 16) * OUT_F + ocol], c1[r] + bv);
    }
}

extern "C" void kernel_launch(void* const* d_in, const int* in_sizes, int n_in,
                              void* d_out, int out_size, void* d_ws, size_t ws_size,
                              hipStream_t stream) {
    (void)in_sizes; (void)n_in; (void)out_size; (void)ws_size;
    const float* x       = (const float*)d_in[0];
    const int*   indices = (const int*)d_in[1];
    const float* cb      = (const float*)d_in[2];
    const float* R       = (const float*)d_in[3];
    const float* bias    = (const float*)d_in[4];
    float* out  = (float*)d_out;
    float* y_ws = (float*)d_ws;                                  // 512 KB
    int*  flags  = (int*)((char*)d_ws + 512 * 1024);             // 16 ints
    int*  ticket = (int*)((char*)d_ws + 512 * 1024 + 64);        // 1 int

    // zero: y accumulator + flags + ticket (one span), and out (atomic target)
    hipMemsetAsync(d_ws, 0, 512 * 1024 + 128, stream);
    hipMemsetAsync(out, 0, (size_t)BATCH * OUT_F * sizeof(float), stream);
    fused<<<dim3(2048), dim3(256), 0, stream>>>(x, indices, cb, R, bias,
                                                out, y_ws, flags, ticket);
}

// Round 6
// 238.326 us; speedup vs baseline: 3.6281x; 3.6281x over previous
//
#include <hip/hip_runtime.h>
#include <hip/hip_bf16.h>

// out = (x @ R^T) @ codes^T + bias, where codes = codebook[indices]
// x: [32,4096] f32, indices: [8192,4096] i32(0..15), codebook:[16] f32,
// R: [4096,4096] f32, bias: [8192] f32, out: [32,8192] f32.
//
// memset: y_ws = 0 (512 KB)
// K1: out = bias (prologue) ; y_ws += x @ R^T   (bf16 MFMA, ksplit 16, front-loaded vmem)
// K2: out += y @ codes^T                        (bf16 MFMA, ksplit 16, front-loaded vmem)
//
// NOTE (R5 post-mortem): do NOT fuse K1/K2 with global-memory flags. The
// device-scope release/acquire fences required by cross-XCD non-coherence
// lower to L2 writeback/invalidate per block -> 750 us, HBM at 2% peak.

#define IN_F 4096
#define OUT_F 8192
#define BATCH 32
#define TS 264   // LDS row stride in bf16 elems: 528 B = 33*16 B (16B-aligned rows, bank-rotated)

typedef short bf16x8s __attribute__((ext_vector_type(8)));   // 8 bf16 in 4 VGPRs
typedef float f32x4 __attribute__((ext_vector_type(4)));
typedef int   i32x4 __attribute__((ext_vector_type(4)));

// fp32 -> bf16 bits, round-to-nearest-even
__device__ __forceinline__ unsigned short f2bf(float f) {
    union { float f; unsigned int u; } v; v.f = f;
    unsigned int u = v.u;
    return (unsigned short)((u + 0x7fffu + ((u >> 16) & 1u)) >> 16);
}

// ---------------- K1: y = x @ R^T (bf16 MFMA), out=bias prologue ----------------
// grid = 64 j-tiles * 16 k-splits = 1024 blocks, 256 threads (4 waves)
__global__ void __launch_bounds__(256, 3) k1_xRT(const float* __restrict__ x,
                                                 const float* __restrict__ R,
                                                 const float* __restrict__ bias,
                                                 float* __restrict__ out,
                                                 float* __restrict__ y_ws) {
    __shared__ unsigned short Bl[64 * TS];  // R tile  [64 j][256 k] bf16
    __shared__ unsigned short Al[32 * TS];  // x tile  [32 b][256 k] bf16

    const int tid  = threadIdx.x;
    const int jt   = blockIdx.x & 63;
    const int kq   = blockIdx.x >> 6;     // 0..15
    const int j0   = jt * 64;
    const int k0   = kq * 256;
    const int wave = tid >> 6, lane = tid & 63;
    const int n = lane & 15, quad = lane >> 4;

    // ---- issue ALL global loads first (R is stream-once -> nontemporal) ----
    f32x4 rv[16];
    #pragma unroll
    for (int jj = 0; jj < 16; ++jj) {
        int f = tid + jj * 256;              // [64 rows][64 float4]
        int row = f >> 6, c4 = f & 63;
        rv[jj] = __builtin_nontemporal_load(
            (const f32x4*)(R + (size_t)(j0 + row) * IN_F + k0 + c4 * 4));
    }
    f32x4 xv[8];
    #pragma unroll
    for (int ii = 0; ii < 8; ++ii) {
        int f = tid + ii * 256;              // [32 rows][64 float4]
        int row = f >> 6, c4 = f & 63;
        xv[ii] = *(const f32x4*)(x + (size_t)row * IN_F + k0 + c4 * 4);
    }
    // out = bias init: 262144 elems over 1024 blocks = 1/thread (before K2's atomics)
    {
        int id = blockIdx.x * 256 + tid;
        out[id] = bias[id & (OUT_F - 1)];
    }

    // ---- convert + LDS write ----
    #pragma unroll
    for (int jj = 0; jj < 16; ++jj) {
        int f = tid + jj * 256;
        int row = f >> 6, c4 = f & 63;
        ushort4 pv;
        pv.x = f2bf(rv[jj].x); pv.y = f2bf(rv[jj].y);
        pv.z = f2bf(rv[jj].z); pv.w = f2bf(rv[jj].w);
        *(ushort4*)&Bl[row * TS + c4 * 4] = pv;
    }
    #pragma unroll
    for (int ii = 0; ii < 8; ++ii) {
        int f = tid + ii * 256;
        int row = f >> 6, c4 = f & 63;
        ushort4 pv;
        pv.x = f2bf(xv[ii].x); pv.y = f2bf(xv[ii].y);
        pv.z = f2bf(xv[ii].z); pv.w = f2bf(xv[ii].w);
        *(ushort4*)&Al[row * TS + c4 * 4] = pv;
    }
    __syncthreads();

    f32x4 acc0 = {0.f, 0.f, 0.f, 0.f};
    f32x4 acc1 = {0.f, 0.f, 0.f, 0.f};
    #pragma unroll
    for (int ks = 0; ks < 8; ++ks) {
        bf16x8s bfr = *(const bf16x8s*)&Bl[(wave * 16 + n) * TS + ks * 32 + quad * 8];
        bf16x8s a0  = *(const bf16x8s*)&Al[n * TS + ks * 32 + quad * 8];
        bf16x8s a1  = *(const bf16x8s*)&Al[(16 + n) * TS + ks * 32 + quad * 8];
        acc0 = __builtin_amdgcn_mfma_f32_16x16x32_bf16(a0, bfr, acc0, 0, 0, 0);
        acc1 = __builtin_amdgcn_mfma_f32_16x16x32_bf16(a1, bfr, acc1, 0, 0, 0);
    }

    // C/D layout: col=lane&15 (n), row=quad*4+r (m)
    const int jcol = j0 + wave * 16 + n;
    #pragma unroll
    for (int r = 0; r < 4; ++r) {
        int br = quad * 4 + r;
        atomicAdd(&y_ws[(size_t)br * IN_F + jcol], acc0[r]);
        atomicAdd(&y_ws[(size_t)(br + 16) * IN_F + jcol], acc1[r]);
    }
}

// ---------------- K2: out += y @ codes^T (bf16 MFMA, fused dequant) ----------------
// grid = 128 o-tiles * 16 k-splits = 2048 blocks, 256 threads (4 waves)
__global__ void __launch_bounds__(256, 3) k2_out(const int* __restrict__ idx,
                                                 const float* __restrict__ cb,
                                                 const float* __restrict__ yws,
                                                 float* __restrict__ out) {
    __shared__ unsigned short Bl[64 * TS];  // codes tile [64 o][256 k] bf16
    __shared__ unsigned short Al[32 * TS];  // y tile     [32 b][256 k] bf16
    __shared__ unsigned int cbp[256];       // pair table: (i,j) -> bf16(cb[i]) | bf16(cb[j])<<16

    const int tid = threadIdx.x;
    const int ot = blockIdx.x & 127;
    const int kq = blockIdx.x >> 7;       // 0..15
    const int o0 = ot * 64;
    const int k0 = kq * 256;
    const int wave = tid >> 6, lane = tid & 63;
    const int n = lane & 15, quad = lane >> 4;

    // ---- issue ALL global loads first (idx is stream-once -> nontemporal) ----
    i32x4 iv[16];
    #pragma unroll
    for (int jj = 0; jj < 16; ++jj) {
        int f = tid + jj * 256;              // [64 rows][64 int4]
        int row = f >> 6, c4 = f & 63;
        iv[jj] = __builtin_nontemporal_load(
            (const i32x4*)(idx + (size_t)(o0 + row) * IN_F + k0 + c4 * 4));
    }
    f32x4 fv[8];
    #pragma unroll
    for (int ii = 0; ii < 8; ++ii) {
        int f = tid + ii * 256;              // [32 rows][64 float4]
        int row = f >> 6, c4 = f & 63;
        fv[ii] = *(const f32x4*)(yws + (size_t)row * IN_F + k0 + c4 * 4);
    }

    // dequant pair table (loads overlap the barrier below)
    {
        unsigned int lo = f2bf(cb[tid & 15]);
        unsigned int hi = f2bf(cb[tid >> 4]);
        cbp[tid] = lo | (hi << 16);
    }
    __syncthreads();   // cbp visible; idx/y loads still in flight

    // ---- convert + LDS write ----
    #pragma unroll
    for (int jj = 0; jj < 16; ++jj) {
        int f = tid + jj * 256;
        int row = f >> 6, c4 = f & 63;
        unsigned int key0 = (unsigned int)iv[jj].x | ((unsigned int)iv[jj].y << 4);
        unsigned int key1 = (unsigned int)iv[jj].z | ((unsigned int)iv[jj].w << 4);
        uint2 pv;
        pv.x = cbp[key0];
        pv.y = cbp[key1];
        *(uint2*)&Bl[row * TS + c4 * 4] = pv;
    }
    #pragma unroll
    for (int ii = 0; ii < 8; ++ii) {
        int f = tid + ii * 256;
        int row = f >> 6, c4 = f & 63;
        ushort4 pv;
        pv.x = f2bf(fv[ii].x); pv.y = f2bf(fv[ii].y);
        pv.z = f2bf(fv[ii].z); pv.w = f2bf(fv[ii].w);
        *(ushort4*)&Al[row * TS + c4 * 4] = pv;
    }
    __syncthreads();

    f32x4 acc0 = {0.f, 0.f, 0.f, 0.f};
    f32x4 acc1 = {0.f, 0.f, 0.f, 0.f};
    #pragma unroll
    for (int ks = 0; ks < 8; ++ks) {
        bf16x8s bfr = *(const bf16x8s*)&Bl[(wave * 16 + n) * TS + ks * 32 + quad * 8];
        bf16x8s a0  = *(const bf16x8s*)&Al[n * TS + ks * 32 + quad * 8];
        bf16x8s a1  = *(const bf16x8s*)&Al[(16 + n) * TS + ks * 32 + quad * 8];
        acc0 = __builtin_amdgcn_mfma_f32_16x16x32_bf16(a0, bfr, acc0, 0, 0, 0);
        acc1 = __builtin_amdgcn_mfma_f32_16x16x32_bf16(a1, bfr, acc1, 0, 0, 0);
    }

    const int ocol = o0 + wave * 16 + n;
    #pragma unroll
    for (int r = 0; r < 4; ++r) {
        int br = quad * 4 + r;
        atomicAdd(&out[(size_t)br * OUT_F + ocol], acc0[r]);
        atomicAdd(&out[(size_t)(br + 16) * OUT_F + ocol], acc1[r]);
    }
}

extern "C" void kernel_launch(void* const* d_in, const int* in_sizes, int n_in,
                              void* d_out, int out_size, void* d_ws, size_t ws_size,
                              hipStream_t stream) {
    (void)in_sizes; (void)n_in; (void)out_size; (void)ws_size;
    const float* x       = (const float*)d_in[0];
    const int*   indices = (const int*)d_in[1];
    const float* cb      = (const float*)d_in[2];
    const float* R       = (const float*)d_in[3];
    const float* bias    = (const float*)d_in[4];
    float* out  = (float*)d_out;
    float* y_ws = (float*)d_ws;           // 32*4096 f32 = 512 KB scratch

    hipMemsetAsync(y_ws, 0, (size_t)BATCH * IN_F * sizeof(float), stream);
    k1_xRT<<<dim3(1024), dim3(256), 0, stream>>>(x, R, bias, out, y_ws);
    k2_out<<<dim3(2048), dim3(256), 0, stream>>>(indices, cb, y_ws, out);
}